// Round 12
// baseline (138.780 us; speedup 1.0000x reference)
//
#include <hip/hip_runtime.h>

#define Bdim 2
#define Sdim 2048
#define Ddim 1024
#define Hdim 16

typedef unsigned short u16;
typedef u16 u16x8 __attribute__((ext_vector_type(8)));
typedef u16 u16x4 __attribute__((ext_vector_type(4)));
typedef unsigned u32x4 __attribute__((ext_vector_type(4)));
typedef __bf16 bf16x8 __attribute__((ext_vector_type(8)));
typedef float f32x4 __attribute__((ext_vector_type(4)));
typedef float f32x16 __attribute__((ext_vector_type(16)));

static __device__ __forceinline__ u16 f2bf(float f) {
  unsigned u = __float_as_uint(f);
  u += 0x7fffu + ((u >> 16) & 1u);
  return (u16)(u >> 16);
}
static __device__ __forceinline__ bf16x8 asbf(u16x8 v) {
  return __builtin_bit_cast(bf16x8, v);
}
static __device__ __forceinline__ f32x4 mfma16(bf16x8 a, bf16x8 b, f32x4 c) {
  return __builtin_amdgcn_mfma_f32_16x16x32_bf16(a, b, c, 0, 0, 0);
}
static __device__ __forceinline__ f32x16 mfma32(bf16x8 a, bf16x8 b, f32x16 c) {
  return __builtin_amdgcn_mfma_f32_32x32x16_bf16(a, b, c, 0, 0, 0);
}

// async global->LDS, 16B/lane. LDS dest = wave-uniform base + lane*16 (m104/m108).
#define GLD16(gp, lp)                                                   \
  __builtin_amdgcn_global_load_lds(                                     \
      (const __attribute__((address_space(1))) void*)(gp),              \
      (__attribute__((address_space(3))) void*)(lp), 16, 0, 0)

// ---------------- cast x (f32 -> bf16), 8 elems/thread ----------------
__global__ __launch_bounds__(256) void cvtx(const float* __restrict__ x,
                                            u16* __restrict__ xb) {
  int i = blockIdx.x * 256 + threadIdx.x;
  const float4* xp = (const float4*)x;
  float4 a = xp[2 * i], b = xp[2 * i + 1];
  u16x8 o;
  o[0] = f2bf(a.x); o[1] = f2bf(a.y); o[2] = f2bf(a.z); o[3] = f2bf(a.w);
  o[4] = f2bf(b.x); o[5] = f2bf(b.y); o[6] = f2bf(b.z); o[7] = f2bf(b.w);
  ((u16x8*)xb)[i] = o;
}

// ---------------- transpose + cast W [K][N] f32 -> WT [N][K] bf16 ----------------
__global__ __launch_bounds__(256) void transw(
    const float* __restrict__ W0, const float* __restrict__ W1,
    const float* __restrict__ W2, const float* __restrict__ W3,
    u16* __restrict__ T0, u16* __restrict__ T1,
    u16* __restrict__ T2, u16* __restrict__ T3) {
  const float* W = blockIdx.z == 0 ? W0 : blockIdx.z == 1 ? W1 : blockIdx.z == 2 ? W2 : W3;
  u16* T = blockIdx.z == 0 ? T0 : blockIdx.z == 1 ? T1 : blockIdx.z == 2 ? T2 : T3;
  __shared__ float tile[32][33];
  const int t = threadIdx.x;
  const int k0 = blockIdx.x * 32, n0 = blockIdx.y * 32;
  const int r = t >> 3, cq = (t & 7) * 4;
  float4 v = *(const float4*)(W + (size_t)(k0 + r) * Ddim + n0 + cq);
  tile[r][cq] = v.x; tile[r][cq + 1] = v.y; tile[r][cq + 2] = v.z; tile[r][cq + 3] = v.w;
  __syncthreads();
  u16x4 ov;
  ov[0] = f2bf(tile[cq][r]);
  ov[1] = f2bf(tile[cq + 1][r]);
  ov[2] = f2bf(tile[cq + 2][r]);
  ov[3] = f2bf(tile[cq + 3][r]);
  *(u16x4*)(T + (size_t)(n0 + r) * Ddim + k0 + cq) = ov;
}

// -------- transpose V [B,S,D] -> fragment-tiled Vt[bh][kt][c][dh] directly --------
// Vt chunk ((bh*32+kt)*8+c)*64+dh holds VT[bh][dh][kt*64+c*8 .. +8] (8 seq positions).
__global__ __launch_bounds__(256) void vtrans(const u16* __restrict__ V,
                                              u16* __restrict__ Vt) {
  __shared__ u16 tile[32][72];
  const int t = threadIdx.x;
  const int s0 = blockIdx.x * 32;
  const int bh = blockIdx.y, b = bh >> 4, h = bh & 15;
  {
    int sl = t >> 3, dq = (t & 7) * 8;
    u16x8 v = *(const u16x8*)(V + (size_t)(b * Sdim + s0 + sl) * Ddim + h * 64 + dq);
    *(u16x8*)(&tile[sl][dq]) = v;
  }
  __syncthreads();
  {
    int dl = t >> 2, sq = (t & 3) * 8;
    u16x8 v;
#pragma unroll
    for (int i = 0; i < 8; i++) v[i] = tile[sq + i][dl];
    int s = s0 + sq;
    int kt = s >> 6, c = (s >> 3) & 7;
    *(u16x8*)(Vt + ((((size_t)bh * 32 + kt) * 8 + c) * 64 + dl) * 8) = v;
  }
}

// -------- tile K into fragment-ordered Kt[bh][kt][c][row] --------
// chunk = K[b][kt*64+row][h*64+c*8 .. +8]; attn reads 2 contiguous 512B runs/instr.
__global__ __launch_bounds__(256) void tilek(const u16* __restrict__ K,
                                             u16* __restrict__ Kt) {
  int tid = blockIdx.x * 256 + threadIdx.x;  // 0 .. 524287
  int row = tid & 63;
  int c = (tid >> 6) & 7;
  int kt = (tid >> 9) & 31;
  int bh = tid >> 14;
  int b = bh >> 4, h = bh & 15;
  u16x8 kc = *(const u16x8*)(K + (size_t)(b * Sdim + kt * 64 + row) * Ddim + h * 64 + c * 8);
  ((u16x8*)Kt)[tid] = kc;
}

// ---------------- 128x128 bf16 MFMA GEMM — m97-EXACT structure ----------------
// GLD16 width-16 with LINEAR source + LINEAR LDS + LINEAR ds_read (no swizzle:
// rule #21 "both-sides-or-neither"; T2 swizzle is NULL at 128^2+2-phase per the
// regime gate m228d/m233 — critical path is the stage+barrier drain, so the
// 16-way ds_read conflict is hidden). Measured 874 TF at this exact shape (m97).
// Merged-N launch: blockIdx.y = (z<<3)|n-tile -> QKV is ONE 768-block dispatch.
template <bool F32OUT>
__global__ __launch_bounds__(256) void gemm128(
    const u16* __restrict__ A,
    const u16* __restrict__ Bt0, const u16* __restrict__ Bt1, const u16* __restrict__ Bt2,
    void* __restrict__ C0v, void* __restrict__ C1v, void* __restrict__ C2v) {
  __shared__ u16 As[128 * 64];
  __shared__ u16 Bs[128 * 64];
  const int zz = blockIdx.y >> 3;
  const u16* Bt = (zz == 0) ? Bt0 : (zz == 1) ? Bt1 : Bt2;
  void* Cv = (zz == 0) ? C0v : (zz == 1) ? C1v : C2v;

  const int t = threadIdx.x;
  const int lane = t & 63, w = t >> 6;
  const int wm = w >> 1, wn = w & 1;
  const int c = lane & 15, g = lane >> 4;
  const int m0 = blockIdx.x * 128, n0 = (blockIdx.y & 7) * 128;
  // Q projection gets the 1/sqrt(DH)=0.125 scale folded in (zz==0 of the QKV gemm).
  const float oscale = (!F32OUT && zz == 0) ? 0.125f : 1.0f;

  const f32x4 zv = {0.f, 0.f, 0.f, 0.f};
  f32x4 acc[4][4];
#pragma unroll
  for (int m = 0; m < 4; m++)
#pragma unroll
    for (int n = 0; n < 4; n++) acc[m][n] = zv;

  const int r8 = lane >> 3, ch = lane & 7;  // staging: 8 rows x 8 chunks per instr
  for (int kt = 0; kt < 1024; kt += 64) {
    __syncthreads();
#pragma unroll
    for (int i = 0; i < 4; i++) {
      int rowbase = w * 32 + i * 8;
      GLD16(A + (size_t)(m0 + rowbase + r8) * 1024 + kt + ch * 8, As + rowbase * 64);
      GLD16(Bt + (size_t)(n0 + rowbase + r8) * 1024 + kt + ch * 8, Bs + rowbase * 64);
    }
    __syncthreads();  // drains vmcnt -> staged data visible
#pragma unroll
    for (int kh = 0; kh < 2; kh++) {
      bf16x8 af[4], bfr[4];
#pragma unroll
      for (int m = 0; m < 4; m++) {
        int row = wm * 64 + m * 16 + c;
        af[m] = asbf(*(const u16x8*)(As + row * 64 + (kh * 4 + g) * 8));
      }
#pragma unroll
      for (int n = 0; n < 4; n++) {
        int row = wn * 64 + n * 16 + c;
        bfr[n] = asbf(*(const u16x8*)(Bs + row * 64 + (kh * 4 + g) * 8));
      }
#pragma unroll
      for (int m = 0; m < 4; m++)
#pragma unroll
        for (int n = 0; n < 4; n++) acc[m][n] = mfma16(af[m], bfr[n], acc[m][n]);
    }
  }
  // epilogue: C/D layout col=lane&15, row=4*(lane>>4)+r  [measured m89/m91]
#pragma unroll
  for (int m = 0; m < 4; m++)
#pragma unroll
    for (int n = 0; n < 4; n++)
#pragma unroll
      for (int r = 0; r < 4; r++) {
        int row = m0 + wm * 64 + m * 16 + 4 * g + r;
        int col = n0 + wn * 64 + n * 16 + c;
        if (F32OUT)
          ((float*)Cv)[(size_t)row * 1024 + col] = acc[m][n][r];
        else
          ((u16*)Cv)[(size_t)row * 1024 + col] = f2bf(acc[m][n][r] * oscale);
      }
}

// ---------------- flash attention (r11-verified): swapped 32x32, tiled K/V ----------------
__global__ __launch_bounds__(64, 3) void attn_kernel(
    const u16* __restrict__ Q, const u16* __restrict__ Kt,
    const u16* __restrict__ Vt, const int* __restrict__ vlen,
    u16* __restrict__ O) {
  __shared__ u16 ot[32][72];
  const int lane = threadIdx.x;
  const int q = lane & 31, hi = lane >> 5;
  const int bh = blockIdx.y, b = bh >> 4, h = bh & 15;
  const int q0 = blockIdx.x * 32;
  const int nv = vlen[b];

  // Q fragments (Q pre-scaled by 0.125 in the projection GEMM)
  bf16x8 qf[4];
  {
    const u16* qp = Q + (size_t)(b * Sdim + q0 + q) * Ddim + h * 64 + hi * 8;
#pragma unroll
    for (int s = 0; s < 4; s++) qf[s] = asbf(*(const u16x8*)(qp + s * 16));
  }

  f32x16 o0, o1;
#pragma unroll
  for (int r = 0; r < 16; r++) { o0[r] = 0.f; o1[r] = 0.f; }
  float m = -3.0e38f, l = 0.f;

  const int ktiles = (nv + 63) >> 6;
  for (int kt = 0; kt < ktiles; ++kt) {
    const int k0 = kt * 64;
    const u16* Ktile = Kt + ((size_t)bh * 32 + kt) * 4096;
    const u16* Vtile = Vt + ((size_t)bh * 32 + kt) * 4096;
    // --- QK^T: A=K rows (key), B=Q cols (query=lane&31) ---
    f32x16 sc[2];
#pragma unroll
    for (int kb = 0; kb < 2; kb++) {
      f32x16 acc;
#pragma unroll
      for (int r = 0; r < 16; r++) acc[r] = 0.f;
#pragma unroll
      for (int s = 0; s < 4; s++) {
        bf16x8 kf = asbf(*(const u16x8*)(Ktile + (2 * s + hi) * 512 + (kb * 32 + q) * 8));
        acc = mfma32(kf, qf[s], acc);
      }
      sc[kb] = acc;
    }
    // --- mask (tail tile only); key = k0+kb*32+crow(r,hi) ---
    if (k0 + 64 > nv) {
#pragma unroll
      for (int kb = 0; kb < 2; kb++)
#pragma unroll
        for (int r = 0; r < 16; r++) {
          int key = k0 + kb * 32 + (r & 3) + 8 * (r >> 2) + 4 * hi;
          if (key >= nv) sc[kb][r] = -1e30f;
        }
    }
    // --- row max: tree over 32 in-register + partner lane ---
    float mx[16];
#pragma unroll
    for (int r = 0; r < 16; r++) mx[r] = fmaxf(sc[0][r], sc[1][r]);
#pragma unroll
    for (int st = 8; st > 0; st >>= 1)
#pragma unroll
      for (int r = 0; r < st; r++) mx[r] = fmaxf(mx[r], mx[r + st]);
    float tm = fmaxf(mx[0], __shfl_xor(mx[0], 32));
    // --- defer-max (T13): rescale only when max grew by >8 ---
    if (!__all(tm <= m + 8.f)) {
      float mn = fmaxf(m, tm);
      float al = __expf(m - mn);
#pragma unroll
      for (int r = 0; r < 16; r++) { o0[r] *= al; o1[r] *= al; }
      l *= al;
      m = mn;
    }
    // --- P = exp(sc - m), packed straight to bf16 pairs (cvt_pk) ---
    unsigned pw[4][4];
    float s0 = 0.f, s1 = 0.f, s2 = 0.f, s3 = 0.f;
#pragma unroll
    for (int kb = 0; kb < 2; kb++)
#pragma unroll
      for (int hh = 0; hh < 2; hh++)
#pragma unroll
        for (int wi = 0; wi < 4; wi++) {
          float e0 = __expf(sc[kb][hh * 8 + wi * 2] - m);
          float e1 = __expf(sc[kb][hh * 8 + wi * 2 + 1] - m);
          if (wi == 0) s0 += e0 + e1;
          else if (wi == 1) s1 += e0 + e1;
          else if (wi == 2) s2 += e0 + e1;
          else s3 += e0 + e1;
          asm("v_cvt_pk_bf16_f32 %0, %1, %2"
              : "=v"(pw[kb * 2 + hh][wi]) : "v"(e0), "v"(e1));
        }
    float ssum = (s0 + s1) + (s2 + s3);
    ssum += __shfl_xor(ssum, 32);
    l += ssum;
    // --- redistribute P into B-fragment layout: 2 permlane32_swap per frag ---
#pragma unroll
    for (int f = 0; f < 4; f++) {
      asm("v_permlane32_swap_b32 %0, %1" : "+v"(pw[f][0]), "+v"(pw[f][2]));
      asm("v_permlane32_swap_b32 %0, %1" : "+v"(pw[f][1]), "+v"(pw[f][3]));
    }
    // --- PV as O^T = VT @ P: A=VT rows (dh), B=P cols (query) ---
#pragma unroll
    for (int f = 0; f < 4; f++) {
      u32x4 wv = {pw[f][0], pw[f][1], pw[f][2], pw[f][3]};
      bf16x8 pa = __builtin_bit_cast(bf16x8, wv);
      bf16x8 va = asbf(*(const u16x8*)(Vtile + (2 * f + hi) * 512 + q * 8));
      bf16x8 vb = asbf(*(const u16x8*)(Vtile + (2 * f + hi) * 512 + (32 + q) * 8));
      o0 = mfma32(va, pa, o0);
      o1 = mfma32(vb, pa, o1);
    }
  }
  // --- epilogue: normalize (lane-local l), transpose via LDS, coalesced store ---
  const float linv = 1.f / l;
#pragma unroll
  for (int r = 0; r < 16; r++) {
    const int dh = (r & 3) + 8 * (r >> 2) + 4 * hi;
    ot[q][dh] = f2bf(o0[r] * linv);
    ot[q][32 + dh] = f2bf(o1[r] * linv);
  }
  asm volatile("s_waitcnt lgkmcnt(0)" ::: "memory");
  __builtin_amdgcn_sched_barrier(0);
  {
    u16* op = O + (size_t)(b * Sdim + q0 + q) * Ddim + h * 64 + hi * 32;
#pragma unroll
    for (int j = 0; j < 4; j++)
      *(u16x8*)(op + j * 8) = *(const u16x8*)(&ot[q][hi * 32 + j * 8]);
  }
}

extern "C" void kernel_launch(void* const* d_in, const int* in_sizes, int n_in,
                              void* d_out, int out_size, void* d_ws, size_t ws_size,
                              hipStream_t stream) {
  const float* x = (const float*)d_in[0];
  const float* Wq = (const float*)d_in[1];
  const float* Wk = (const float*)d_in[2];
  const float* Wv = (const float*)d_in[3];
  const float* Wo = (const float*)d_in[4];
  const int* vl = (const int*)d_in[5];
  float* out = (float*)d_out;

  char* ws = (char*)d_ws;
  const size_t SZ_X = (size_t)Bdim * Sdim * Ddim * sizeof(u16);  // 8 MB
  const size_t SZ_W = (size_t)Ddim * Ddim * sizeof(u16);         // 2 MB
  u16* xb = (u16*)ws; ws += SZ_X;
  u16* WqT = (u16*)ws; ws += SZ_W;
  u16* WkT = (u16*)ws; ws += SZ_W;
  u16* WvT = (u16*)ws; ws += SZ_W;
  u16* WoT = (u16*)ws; ws += SZ_W;
  u16* Qb = (u16*)ws; ws += SZ_X;
  u16* Kb = (u16*)ws; ws += SZ_X;
  u16* Vb = (u16*)ws; ws += SZ_X;
  u16* Ob = (u16*)ws; ws += SZ_X;
  u16* Ktb = (u16*)ws; ws += SZ_X;  // fragment-tiled K
  u16* Vtb = (u16*)ws; ws += SZ_X;  // fragment-tiled V^T

  cvtx<<<dim3((Bdim * Sdim * Ddim) / (8 * 256)), 256, 0, stream>>>(x, xb);
  transw<<<dim3(32, 32, 4), 256, 0, stream>>>(Wq, Wk, Wv, Wo, WqT, WkT, WvT, WoT);
  // QKV as ONE dispatch: grid.y = 24 -> (z = y>>3, n-tile = y&7); 768 blocks = 3/CU.
  gemm128<false><<<dim3(32, 24), 256, 0, stream>>>(xb, WqT, WkT, WvT, Qb, Kb, Vb);
  vtrans<<<dim3(Sdim / 32, Bdim * Hdim), 256, 0, stream>>>(Vb, Vtb);
  tilek<<<dim3((Bdim * Sdim * Ddim / 8) / 256), 256, 0, stream>>>(Kb, Ktb);
  attn_kernel<<<dim3(Sdim / 32, Bdim * Hdim), 64, 0, stream>>>(Qb, Ktb, Vtb, vl, Ob);
  gemm128<true><<<dim3(32, 8), 256, 0, stream>>>(Ob, WoT, WoT, WoT, out, out, out);
}

// Round 13
// 130.328 us; speedup vs baseline: 1.0648x; 1.0648x over previous
//
#include <hip/hip_runtime.h>

#define Bdim 2
#define Sdim 2048
#define Ddim 1024
#define Hdim 16

typedef unsigned short u16;
typedef u16 u16x8 __attribute__((ext_vector_type(8)));
typedef u16 u16x4 __attribute__((ext_vector_type(4)));
typedef unsigned u32x4 __attribute__((ext_vector_type(4)));
typedef __bf16 bf16x8 __attribute__((ext_vector_type(8)));
typedef float f32x4 __attribute__((ext_vector_type(4)));
typedef float f32x16 __attribute__((ext_vector_type(16)));

static __device__ __forceinline__ u16 f2bf(float f) {
  unsigned u = __float_as_uint(f);
  u += 0x7fffu + ((u >> 16) & 1u);
  return (u16)(u >> 16);
}
static __device__ __forceinline__ float bf2f(u16 v) {
  return __uint_as_float((unsigned)v << 16);
}
static __device__ __forceinline__ bf16x8 asbf(u16x8 v) {
  return __builtin_bit_cast(bf16x8, v);
}
static __device__ __forceinline__ f32x4 mfma16(bf16x8 a, bf16x8 b, f32x4 c) {
  return __builtin_amdgcn_mfma_f32_16x16x32_bf16(a, b, c, 0, 0, 0);
}
static __device__ __forceinline__ f32x16 mfma32(bf16x8 a, bf16x8 b, f32x16 c) {
  return __builtin_amdgcn_mfma_f32_32x32x16_bf16(a, b, c, 0, 0, 0);
}

// ---------------- cast x (f32 -> bf16), 8 elems/thread ----------------
__global__ __launch_bounds__(256) void cvtx(const float* __restrict__ x,
                                            u16* __restrict__ xb) {
  int i = blockIdx.x * 256 + threadIdx.x;
  const float4* xp = (const float4*)x;
  float4 a = xp[2 * i], b = xp[2 * i + 1];
  u16x8 o;
  o[0] = f2bf(a.x); o[1] = f2bf(a.y); o[2] = f2bf(a.z); o[3] = f2bf(a.w);
  o[4] = f2bf(b.x); o[5] = f2bf(b.y); o[6] = f2bf(b.z); o[7] = f2bf(b.w);
  ((u16x8*)xb)[i] = o;
}

// ---------------- transpose + cast W [K][N] f32 -> WT [N][K] bf16 ----------------
__global__ __launch_bounds__(256) void transw(
    const float* __restrict__ W0, const float* __restrict__ W1,
    const float* __restrict__ W2, const float* __restrict__ W3,
    u16* __restrict__ T0, u16* __restrict__ T1,
    u16* __restrict__ T2, u16* __restrict__ T3) {
  const float* W = blockIdx.z == 0 ? W0 : blockIdx.z == 1 ? W1 : blockIdx.z == 2 ? W2 : W3;
  u16* T = blockIdx.z == 0 ? T0 : blockIdx.z == 1 ? T1 : blockIdx.z == 2 ? T2 : T3;
  __shared__ float tile[32][33];
  const int t = threadIdx.x;
  const int k0 = blockIdx.x * 32, n0 = blockIdx.y * 32;
  const int r = t >> 3, cq = (t & 7) * 4;
  float4 v = *(const float4*)(W + (size_t)(k0 + r) * Ddim + n0 + cq);
  tile[r][cq] = v.x; tile[r][cq + 1] = v.y; tile[r][cq + 2] = v.z; tile[r][cq + 3] = v.w;
  __syncthreads();
  u16x4 ov;
  ov[0] = f2bf(tile[cq][r]);
  ov[1] = f2bf(tile[cq + 1][r]);
  ov[2] = f2bf(tile[cq + 2][r]);
  ov[3] = f2bf(tile[cq + 3][r]);
  *(u16x4*)(T + (size_t)(n0 + r) * Ddim + k0 + cq) = ov;
}

// -------- transpose V [B,S,D] -> fragment-tiled Vt[bh][kt][c][dh] directly --------
__global__ __launch_bounds__(256) void vtrans(const u16* __restrict__ V,
                                              u16* __restrict__ Vt) {
  __shared__ u16 tile[32][72];
  const int t = threadIdx.x;
  const int s0 = blockIdx.x * 32;
  const int bh = blockIdx.y, b = bh >> 4, h = bh & 15;
  {
    int sl = t >> 3, dq = (t & 7) * 8;
    u16x8 v = *(const u16x8*)(V + (size_t)(b * Sdim + s0 + sl) * Ddim + h * 64 + dq);
    *(u16x8*)(&tile[sl][dq]) = v;
  }
  __syncthreads();
  {
    int dl = t >> 2, sq = (t & 3) * 8;
    u16x8 v;
#pragma unroll
    for (int i = 0; i < 8; i++) v[i] = tile[sq + i][dl];
    int s = s0 + sq;
    int kt = s >> 6, c = (s >> 3) & 7;
    *(u16x8*)(Vt + ((((size_t)bh * 32 + kt) * 8 + c) * 64 + dl) * 8) = v;
  }
}

// -------- tile K into fragment-ordered Kt[bh][kt][c][row] --------
__global__ __launch_bounds__(256) void tilek(const u16* __restrict__ K,
                                             u16* __restrict__ Kt) {
  int tid = blockIdx.x * 256 + threadIdx.x;  // 0 .. 524287
  int row = tid & 63;
  int c = (tid >> 6) & 7;
  int kt = (tid >> 9) & 31;
  int bh = tid >> 14;
  int b = bh >> 4, h = bh & 15;
  u16x8 kc = *(const u16x8*)(K + (size_t)(b * Sdim + kt * 64 + row) * Ddim + h * 64 + c * 8);
  ((u16x8*)Kt)[tid] = kc;
}

// ---------------- 128x128 bf16 MFMA GEMM — r11-verified (best measured: 46.2us QKV) ----------------
// Reg-staged swizzled ds_writes + swizzled ds_reads (0 bank conflicts, MfmaUtil 21%).
// r12's m97-exact GLD16+linear REGRESSED to 54.3us / 9.4M conflicts here — the
// 16-way conflict is NOT hidden in this context. Keep the measured winner.
// Merged-N launch: blockIdx.y = (z<<3)|n-tile -> QKV is ONE 768-block dispatch.
template <bool F32OUT>
__global__ __launch_bounds__(256) void gemm128(
    const u16* __restrict__ A,
    const u16* __restrict__ Bt0, const u16* __restrict__ Bt1, const u16* __restrict__ Bt2,
    void* __restrict__ C0v, void* __restrict__ C1v, void* __restrict__ C2v) {
  __shared__ u16 As[128 * 64];
  __shared__ u16 Bs[128 * 64];
  const int zz = blockIdx.y >> 3;
  const u16* Bt = (zz == 0) ? Bt0 : (zz == 1) ? Bt1 : Bt2;
  void* Cv = (zz == 0) ? C0v : (zz == 1) ? C1v : C2v;

  const int t = threadIdx.x;
  const int lane = t & 63, w = t >> 6;
  const int wm = w >> 1, wn = w & 1;
  const int c = lane & 15, g = lane >> 4;
  const int m0 = blockIdx.x * 128, n0 = (blockIdx.y & 7) * 128;
  const float oscale = (!F32OUT && zz == 0) ? 0.125f : 1.0f;

  const f32x4 zv = {0.f, 0.f, 0.f, 0.f};
  f32x4 acc[4][4];
#pragma unroll
  for (int m = 0; m < 4; m++)
#pragma unroll
    for (int n = 0; n < 4; n++) acc[m][n] = zv;

  for (int kt = 0; kt < 1024; kt += 64) {
    __syncthreads();
#pragma unroll
    for (int i = 0; i < 4; i++) {
      int idx = t + 256 * i;  // 0..1023 chunk id
      int row = idx >> 3, ch = idx & 7;
      int sw = (ch ^ (row & 7)) * 8;
      u16x8 va = *(const u16x8*)(A + (size_t)(m0 + row) * 1024 + kt + ch * 8);
      *(u16x8*)(As + row * 64 + sw) = va;
      u16x8 vb = *(const u16x8*)(Bt + (size_t)(n0 + row) * 1024 + kt + ch * 8);
      *(u16x8*)(Bs + row * 64 + sw) = vb;
    }
    __syncthreads();
#pragma unroll
    for (int kh = 0; kh < 2; kh++) {
      bf16x8 af[4], bfr[4];
#pragma unroll
      for (int m = 0; m < 4; m++) {
        int row = wm * 64 + m * 16 + c;
        int chr = kh * 4 + g;
        af[m] = asbf(*(const u16x8*)(As + row * 64 + ((chr ^ (row & 7)) * 8)));
      }
#pragma unroll
      for (int n = 0; n < 4; n++) {
        int row = wn * 64 + n * 16 + c;
        int chr = kh * 4 + g;
        bfr[n] = asbf(*(const u16x8*)(Bs + row * 64 + ((chr ^ (row & 7)) * 8)));
      }
#pragma unroll
      for (int m = 0; m < 4; m++)
#pragma unroll
        for (int n = 0; n < 4; n++) acc[m][n] = mfma16(af[m], bfr[n], acc[m][n]);
    }
  }
  // epilogue: C/D layout col=lane&15, row=4*(lane>>4)+r  [measured m89/m91]
#pragma unroll
  for (int m = 0; m < 4; m++)
#pragma unroll
    for (int n = 0; n < 4; n++)
#pragma unroll
      for (int r = 0; r < 4; r++) {
        int row = m0 + wm * 64 + m * 16 + 4 * g + r;
        int col = n0 + wn * 64 + n * 16 + c;
        if (F32OUT)
          ((float*)Cv)[(size_t)row * 1024 + col] = acc[m][n][r];
        else
          ((u16*)Cv)[(size_t)row * 1024 + col] = f2bf(acc[m][n][r] * oscale);
      }
}

// ---------------- flash attention: tiled K/V (r11-verified body) + KV-split (r7-verified) ----------------
// grid (S/32, B*H, NS). Post-tiling the kernel is latency-bound (~2 waves/SIMD);
// splitting the KV range across NS co-resident blocks buys TLP. NS>1 writes
// unnormalized bf16 O-partial + (m,l); attn_combine merges (exact under defer-max).
__global__ __launch_bounds__(64, 4) void attn_kernel(
    const u16* __restrict__ Q, const u16* __restrict__ Kt,
    const u16* __restrict__ Vt, const int* __restrict__ vlen,
    u16* __restrict__ O, u16* __restrict__ Opart, float2* __restrict__ mlp) {
  __shared__ u16 ot[32][72];
  const int lane = threadIdx.x;
  const int q = lane & 31, hi = lane >> 5;
  const int bh = blockIdx.y, b = bh >> 4, h = bh & 15;
  const int q0 = blockIdx.x * 32;
  const int nv = vlen[b];
  const int NS = gridDim.z, z = blockIdx.z;

  // Q fragments (Q pre-scaled by 0.125 in the projection GEMM)
  bf16x8 qf[4];
  {
    const u16* qp = Q + (size_t)(b * Sdim + q0 + q) * Ddim + h * 64 + hi * 8;
#pragma unroll
    for (int s = 0; s < 4; s++) qf[s] = asbf(*(const u16x8*)(qp + s * 16));
  }

  f32x16 o0, o1;
#pragma unroll
  for (int r = 0; r < 16; r++) { o0[r] = 0.f; o1[r] = 0.f; }
  float m = -3.0e38f, l = 0.f;

  const int nt = (nv + 63) >> 6;
  const int chunk = (nt + NS - 1) / NS;
  const int t0 = z * chunk;
  const int t1 = min(nt, t0 + chunk);
  for (int kt = t0; kt < t1; ++kt) {
    const int k0 = kt * 64;
    const u16* Ktile = Kt + ((size_t)bh * 32 + kt) * 4096;
    const u16* Vtile = Vt + ((size_t)bh * 32 + kt) * 4096;
    // --- QK^T: A=K rows (key), B=Q cols (query=lane&31) ---
    f32x16 sc[2];
#pragma unroll
    for (int kb = 0; kb < 2; kb++) {
      f32x16 acc;
#pragma unroll
      for (int r = 0; r < 16; r++) acc[r] = 0.f;
#pragma unroll
      for (int s = 0; s < 4; s++) {
        bf16x8 kf = asbf(*(const u16x8*)(Ktile + (2 * s + hi) * 512 + (kb * 32 + q) * 8));
        acc = mfma32(kf, qf[s], acc);
      }
      sc[kb] = acc;
    }
    // --- mask (tail tile only); key = k0+kb*32+crow(r,hi) ---
    if (k0 + 64 > nv) {
#pragma unroll
      for (int kb = 0; kb < 2; kb++)
#pragma unroll
        for (int r = 0; r < 16; r++) {
          int key = k0 + kb * 32 + (r & 3) + 8 * (r >> 2) + 4 * hi;
          if (key >= nv) sc[kb][r] = -1e30f;
        }
    }
    // --- row max: tree over 32 in-register + partner lane ---
    float mx[16];
#pragma unroll
    for (int r = 0; r < 16; r++) mx[r] = fmaxf(sc[0][r], sc[1][r]);
#pragma unroll
    for (int st = 8; st > 0; st >>= 1)
#pragma unroll
      for (int r = 0; r < st; r++) mx[r] = fmaxf(mx[r], mx[r + st]);
    float tm = fmaxf(mx[0], __shfl_xor(mx[0], 32));
    // --- defer-max (T13): rescale only when max grew by >8 ---
    if (!__all(tm <= m + 8.f)) {
      float mn = fmaxf(m, tm);
      float al = __expf(m - mn);
#pragma unroll
      for (int r = 0; r < 16; r++) { o0[r] *= al; o1[r] *= al; }
      l *= al;
      m = mn;
    }
    // --- P = exp(sc - m), packed straight to bf16 pairs (cvt_pk) ---
    unsigned pw[4][4];
    float s0 = 0.f, s1 = 0.f, s2 = 0.f, s3 = 0.f;
#pragma unroll
    for (int kb = 0; kb < 2; kb++)
#pragma unroll
      for (int hh = 0; hh < 2; hh++)
#pragma unroll
        for (int wi = 0; wi < 4; wi++) {
          float e0 = __expf(sc[kb][hh * 8 + wi * 2] - m);
          float e1 = __expf(sc[kb][hh * 8 + wi * 2 + 1] - m);
          if (wi == 0) s0 += e0 + e1;
          else if (wi == 1) s1 += e0 + e1;
          else if (wi == 2) s2 += e0 + e1;
          else s3 += e0 + e1;
          asm("v_cvt_pk_bf16_f32 %0, %1, %2"
              : "=v"(pw[kb * 2 + hh][wi]) : "v"(e0), "v"(e1));
        }
    float ssum = (s0 + s1) + (s2 + s3);
    ssum += __shfl_xor(ssum, 32);
    l += ssum;
    // --- redistribute P into B-fragment layout: 2 permlane32_swap per frag ---
#pragma unroll
    for (int f = 0; f < 4; f++) {
      asm("v_permlane32_swap_b32 %0, %1" : "+v"(pw[f][0]), "+v"(pw[f][2]));
      asm("v_permlane32_swap_b32 %0, %1" : "+v"(pw[f][1]), "+v"(pw[f][3]));
    }
    // --- PV as O^T = VT @ P: A=VT rows (dh), B=P cols (query) ---
#pragma unroll
    for (int f = 0; f < 4; f++) {
      u32x4 wv = {pw[f][0], pw[f][1], pw[f][2], pw[f][3]};
      bf16x8 pa = __builtin_bit_cast(bf16x8, wv);
      bf16x8 va = asbf(*(const u16x8*)(Vtile + (2 * f + hi) * 512 + q * 8));
      bf16x8 vb = asbf(*(const u16x8*)(Vtile + (2 * f + hi) * 512 + (32 + q) * 8));
      o0 = mfma32(va, pa, o0);
      o1 = mfma32(vb, pa, o1);
    }
  }
  // --- epilogue ---
  const float scale = (NS == 1) ? (1.f / l) : 1.f;
#pragma unroll
  for (int r = 0; r < 16; r++) {
    const int dh = (r & 3) + 8 * (r >> 2) + 4 * hi;
    ot[q][dh] = f2bf(o0[r] * scale);
    ot[q][32 + dh] = f2bf(o1[r] * scale);
  }
  asm volatile("s_waitcnt lgkmcnt(0)" ::: "memory");
  __builtin_amdgcn_sched_barrier(0);
  if (NS == 1) {
    u16* op = O + (size_t)(b * Sdim + q0 + q) * Ddim + h * 64 + hi * 32;
#pragma unroll
    for (int j = 0; j < 4; j++)
      *(u16x8*)(op + j * 8) = *(const u16x8*)(&ot[q][hi * 32 + j * 8]);
  } else {
    u16* op = Opart + ((size_t)(z * 32 + bh) * Sdim + q0 + q) * 64 + hi * 32;
#pragma unroll
    for (int j = 0; j < 4; j++)
      *(u16x8*)(op + j * 8) = *(const u16x8*)(&ot[q][hi * 32 + j * 8]);
    if (hi == 0)
      mlp[(size_t)(z * 32 + bh) * Sdim + q0 + q] = make_float2(m, l);
  }
}

// ---------------- combine NS split partials: O = sum(w_z O_z) / sum(w_z l_z) ----------------
template <int NS>
__global__ __launch_bounds__(256) void attn_combine(
    const u16* __restrict__ Opart, const float2* __restrict__ mlp,
    u16* __restrict__ O) {
  const int t = threadIdx.x;
  const int bh = blockIdx.y, b = bh >> 4, h = bh & 15;
  const int q = blockIdx.x * 32 + (t >> 3);
  const int d0 = (t & 7) * 8;
  float2 ml[NS];
  float M = -3.0e38f;
#pragma unroll
  for (int z = 0; z < NS; z++) {
    ml[z] = mlp[(size_t)(z * 32 + bh) * Sdim + q];
    M = fmaxf(M, ml[z].x);
  }
  float acc[8];
#pragma unroll
  for (int i = 0; i < 8; i++) acc[i] = 0.f;
  float wsum = 0.f;
#pragma unroll
  for (int z = 0; z < NS; z++) {
    float w = __expf(ml[z].x - M);
    wsum += w * ml[z].y;
    u16x8 ov = *(const u16x8*)(Opart + ((size_t)(z * 32 + bh) * Sdim + q) * 64 + d0);
#pragma unroll
    for (int i = 0; i < 8; i++) acc[i] += w * bf2f(ov[i]);
  }
  const float inv = 1.f / wsum;
  u16x8 res;
#pragma unroll
  for (int i = 0; i < 8; i++) res[i] = f2bf(acc[i] * inv);
  *(u16x8*)(O + ((size_t)b * Sdim + q) * Ddim + h * 64 + d0) = res;
}

extern "C" void kernel_launch(void* const* d_in, const int* in_sizes, int n_in,
                              void* d_out, int out_size, void* d_ws, size_t ws_size,
                              hipStream_t stream) {
  const float* x = (const float*)d_in[0];
  const float* Wq = (const float*)d_in[1];
  const float* Wk = (const float*)d_in[2];
  const float* Wv = (const float*)d_in[3];
  const float* Wo = (const float*)d_in[4];
  const int* vl = (const int*)d_in[5];
  float* out = (float*)d_out;

  char* ws = (char*)d_ws;
  const size_t SZ_X = (size_t)Bdim * Sdim * Ddim * sizeof(u16);  // 8 MB
  const size_t SZ_W = (size_t)Ddim * Ddim * sizeof(u16);         // 2 MB
  u16* xb = (u16*)ws; ws += SZ_X;
  u16* WqT = (u16*)ws; ws += SZ_W;
  u16* WkT = (u16*)ws; ws += SZ_W;
  u16* WvT = (u16*)ws; ws += SZ_W;
  u16* WoT = (u16*)ws; ws += SZ_W;
  u16* Qb = (u16*)ws; ws += SZ_X;
  u16* Kb = (u16*)ws; ws += SZ_X;
  u16* Vb = (u16*)ws; ws += SZ_X;
  u16* Ob = (u16*)ws; ws += SZ_X;
  u16* Ktb = (u16*)ws; ws += SZ_X;  // fragment-tiled K
  u16* Vtb = (u16*)ws; ws += SZ_X;  // fragment-tiled V^T

  // KV-split scratch: per split 8 MB O-partial (bf16) + 0.5 MB (m,l).
  const size_t PER_SPLIT = (size_t)Bdim * Hdim * Sdim * 64 * sizeof(u16) +
                           (size_t)Bdim * Hdim * Sdim * sizeof(float2);
  size_t used = (size_t)(ws - (char*)d_ws);
  size_t avail = (ws_size > used) ? ws_size - used : 0;
  int NS = (avail >= 4 * PER_SPLIT) ? 4 : (avail >= 2 * PER_SPLIT) ? 2 : 1;
  u16* Opart = (u16*)ws;
  float2* mlp = (float2*)(ws + (size_t)NS * Bdim * Hdim * Sdim * 64 * sizeof(u16));

  cvtx<<<dim3((Bdim * Sdim * Ddim) / (8 * 256)), 256, 0, stream>>>(x, xb);
  transw<<<dim3(32, 32, 4), 256, 0, stream>>>(Wq, Wk, Wv, Wo, WqT, WkT, WvT, WoT);
  // QKV as ONE dispatch: grid.y = 24 -> (z = y>>3, n-tile = y&7); 768 blocks = 3/CU.
  gemm128<false><<<dim3(32, 24), 256, 0, stream>>>(xb, WqT, WkT, WvT, Qb, Kb, Vb);
  vtrans<<<dim3(Sdim / 32, Bdim * Hdim), 256, 0, stream>>>(Vb, Vtb);
  tilek<<<dim3((Bdim * Sdim * Ddim / 8) / 256), 256, 0, stream>>>(Kb, Ktb);
  attn_kernel<<<dim3(Sdim / 32, Bdim * Hdim, NS), 64, 0, stream>>>(Qb, Ktb, Vtb, vl, Ob,
                                                                   Opart, mlp);
  if (NS == 4)
    attn_combine<4><<<dim3(Sdim / 32, Bdim * Hdim), 256, 0, stream>>>(Opart, mlp, Ob);
  else if (NS == 2)
    attn_combine<2><<<dim3(Sdim / 32, Bdim * Hdim), 256, 0, stream>>>(Opart, mlp, Ob);
  gemm128<true><<<dim3(32, 8), 256, 0, stream>>>(Ob, WoT, WoT, WoT, out, out, out);
}